// Round 8
// baseline (100.583 us; speedup 1.0000x reference)
//
#include <hip/hip_runtime.h>

// MultiHeadRouter: B=2, L=4096, H=16, S=64, D=128
// out (float32): [T*H ones][T*H argmax-as-float][1 loss], T = 8192
//
// R8: ONE fused kernel (W-convert + MFMA router + loss via last-block-done).
// - f16 2-split MFMA (hh+hl+lh): math chain bit-identical to R4-R7 (absmax 0).
// - W: per-block fp32->f16 hi/lo fragment planes into 32 KB LDS (W is
//   L2-resident: 512 KB total, read-only). Fragment-ordered -> conflict-free
//   ds_read_b128 at lane*16.
// - A: 8 x dwordx4 global->VGPR, issued before W-convert (HBM latency hides
//   under convert VALU).
// - Loss: block partials -> 1024-slot ws via device atomics; last finishing
//   block (counter==2047) reduces ws and writes the scalar. Counter/ws are
//   zeroed by the in-graph memset each call (replay-safe, no cross-call state).

#define TOKENS  8192
#define NHEAD   16
#define NSTATE  64
#define DDIM    128
#define TH      (TOKENS * NHEAD)

typedef _Float16 half8 __attribute__((ext_vector_type(8)));
typedef float    f32x4 __attribute__((ext_vector_type(4)));

constexpr int TPW   = 16;                    // tokens per wave
constexpr int WAVES = 4;
constexpr int TPB   = TPW * WAVES;           // 64 tokens per block
constexpr int BPH   = TOKENS / TPB;          // 128 blocks per head
constexpr int NBLK  = NHEAD * BPH;           // 2048

__device__ __forceinline__ unsigned int ordf(float f) {
    unsigned int u = __float_as_uint(f);
    return (u & 0x80000000u) ? ~u : (u | 0x80000000u);   // order-preserving
}

// RNE f32 -> (f16 hi, f16 lo) split of 8 floats (two f32x4)
__device__ __forceinline__ void split8(const f32x4 v0, const f32x4 v1,
                                       half8& hh, half8& ll) {
    #pragma unroll
    for (int j = 0; j < 4; ++j) {
        _Float16 h0 = (_Float16)v0[j];
        hh[j]     = h0;  ll[j]     = (_Float16)(v0[j] - (float)h0);
        _Float16 h1 = (_Float16)v1[j];
        hh[4 + j] = h1;  ll[4 + j] = (_Float16)(v1[j] - (float)h1);
    }
}

__global__ __launch_bounds__(256)
void router_all(const float* __restrict__ x,     // [T,H,D]
                const float* __restrict__ w,     // [H,S,D]
                const float* __restrict__ bias,  // [H,S]
                float* __restrict__ out,
                float* __restrict__ ws_sums,     // [H,S] = 1024
                int*   __restrict__ ws_cnts,     // [H,S] = 1024
                int*   __restrict__ counter)     // [1], zeroed per call
{
    // [0,32K): 16 B-fragments x 2048 B (hi at +0, lo at +1024 within each).
    // After the MFMA phase the low bytes are reused for block reduction/flag.
    __shared__ __align__(16) unsigned char smem[32768];

    const int blk  = blockIdx.x;
    const int h    = blk >> 7;          // 128 blocks per head
    const int bi   = blk & 127;
    const int tid  = threadIdx.x;
    const int wave = __builtin_amdgcn_readfirstlane(tid >> 6);
    const int lane = tid & 63;
    const int col  = lane & 15;         // A-row within tile == B-state low bits
    const int kg   = lane >> 4;
    const int tokb = bi * TPB + wave * TPW;

    // ---- A: 8 x dwordx4 global->VGPR (HBM; issued first, longest latency) ----
    const size_t srow = (size_t)(NHEAD * DDIM);
    const float* arow = x + (size_t)(tokb + col) * srow + h * DDIM + kg * 8;

    f32x4 g[4][2];
    #pragma unroll
    for (int ks = 0; ks < 4; ++ks) {
        g[ks][0] = *reinterpret_cast<const f32x4*>(arow + ks * 32);
        g[ks][1] = *reinterpret_cast<const f32x4*>(arow + ks * 32 + 4);
    }

    // ---- W: fp32 (L2-hot) -> f16 hi/lo fragment planes in LDS ----
    // element e = (s, c): state s, 8-float chunk c (k0 = c*8).
    // fragment(ks = c>>2, n = s>>4), lane = (s&15) + (c&3)*16.
    #pragma unroll
    for (int i = 0; i < 4; ++i) {
        const int e = i * 256 + tid;
        const int s = e >> 4, c = e & 15;
        const f32x4* wp = reinterpret_cast<const f32x4*>(
            w + (size_t)(h * NSTATE + s) * DDIM + c * 8);
        f32x4 v0 = wp[0], v1 = wp[1];
        half8 hv, lv;
        split8(v0, v1, hv, lv);
        const int off = (((c >> 2) * 4) + (s >> 4)) * 2048
                      + (((s & 15) + (c & 3) * 16) * 16);
        *reinterpret_cast<half8*>(smem + off)        = hv;
        *reinterpret_cast<half8*>(smem + off + 1024) = lv;
    }

    // A split (g dies here; overlaps W-load latency)
    half8 ah[4], al[4];
    #pragma unroll
    for (int ks = 0; ks < 4; ++ks)
        split8(g[ks][0], g[ks][1], ah[ks], al[ks]);

    __syncthreads();   // W planes ready

    f32x4 acc[4];
    #pragma unroll
    for (int n = 0; n < 4; ++n) {
        f32x4 z = {0.f, 0.f, 0.f, 0.f};
        acc[n] = z;
    }

    #pragma unroll
    for (int ks = 0; ks < 4; ++ks) {
        #pragma unroll
        for (int n = 0; n < 4; ++n) {
            const int fo = (ks * 4 + n) * 2048 + lane * 16;
            half8 bh = *reinterpret_cast<const half8*>(smem + fo);
            half8 bl = *reinterpret_cast<const half8*>(smem + fo + 1024);
            // same chain order as R4-R7 (bit-identical results)
            acc[n] = __builtin_amdgcn_mfma_f32_16x16x32_f16(ah[ks], bh, acc[n], 0, 0, 0);
            acc[n] = __builtin_amdgcn_mfma_f32_16x16x32_f16(ah[ks], bl, acc[n], 0, 0, 0);
            acc[n] = __builtin_amdgcn_mfma_f32_16x16x32_f16(al[ks], bh, acc[n], 0, 0, 0);
        }
    }

    // ---- epilogue (R4-R7 absmax-0-verified structure) ----
    // C/D layout: col = lane&15 (state low), row = kg*4 + rg -> token tokb+kg*4+rg
    const float b0 = bias[h * NSTATE +  0 + col];
    const float b1 = bias[h * NSTATE + 16 + col];
    const float b2 = bias[h * NSTATE + 32 + col];
    const float b3 = bias[h * NSTATE + 48 + col];

    float sc[4] = {0.f, 0.f, 0.f, 0.f};
    int   cn[4] = {0, 0, 0, 0};

    #pragma unroll
    for (int rg = 0; rg < 4; ++rg) {
        float L0 = acc[0][rg] + b0;
        float L1 = acc[1][rg] + b1;
        float L2 = acc[2][rg] + b2;
        float L3 = acc[3][rg] + b3;

        // exact argmax, lowest-state tie-break: max of (ord(L)<<6 | (63-s))
        unsigned long long k0 = ((unsigned long long)ordf(L0) << 6) | (unsigned)(63 - ( 0 + col));
        unsigned long long k1 = ((unsigned long long)ordf(L1) << 6) | (unsigned)(63 - (16 + col));
        unsigned long long k2 = ((unsigned long long)ordf(L2) << 6) | (unsigned)(63 - (32 + col));
        unsigned long long k3 = ((unsigned long long)ordf(L3) << 6) | (unsigned)(63 - (48 + col));
        unsigned long long ka = k0 > k1 ? k0 : k1;
        unsigned long long kb = k2 > k3 ? k2 : k3;
        unsigned long long kk = ka > kb ? ka : kb;
        #pragma unroll
        for (int d = 1; d <= 8; d <<= 1) {
            unsigned long long o = __shfl_xor(kk, d);
            kk = kk > o ? kk : o;
        }
        const int idx = 63 - (int)(kk & 63ull);

        // softmax scores (no max-subtract: |logit| << 88); feeds loss only
        float e0 = __expf(L0), e1 = __expf(L1), e2 = __expf(L2), e3 = __expf(L3);
        float sm = (e0 + e1) + (e2 + e3);
        #pragma unroll
        for (int d = 1; d <= 8; d <<= 1) sm += __shfl_xor(sm, d);
        const float rinv = __builtin_amdgcn_rcpf(sm);
        sc[0] += e0 * rinv; sc[1] += e1 * rinv;
        sc[2] += e2 * rinv; sc[3] += e3 * rinv;

        cn[0] += (idx ==  0 + col);
        cn[1] += (idx == 16 + col);
        cn[2] += (idx == 32 + col);
        cn[3] += (idx == 48 + col);

        if (col == 0) {
            const int t = tokb + (kg << 2) + rg;
            out[(size_t)t * NHEAD + h] = 1.0f;
            out[(size_t)TH + (size_t)t * NHEAD + h] = (float)idx;
        }
    }

    // wave-level reduction over the 4 kg groups
    #pragma unroll
    for (int n = 0; n < 4; ++n) {
        sc[n] += __shfl_xor(sc[n], 16);
        sc[n] += __shfl_xor(sc[n], 32);
        cn[n] += __shfl_xor(cn[n], 16);
        cn[n] += __shfl_xor(cn[n], 32);
    }

    // block-level reduction in LDS (B fragments are dead)
    __syncthreads();
    float* redf = (float*)smem;            // [4][64] bytes [0,1024)
    int*   redi = (int*)(smem + 1024);     // [4][64] bytes [1024,2048)
    volatile int* flag = (volatile int*)(smem + 2048);
    float* redl = (float*)(smem + 2064);   // loss partials [4]
    if (kg == 0) {
        #pragma unroll
        for (int n = 0; n < 4; ++n) {
            redf[wave * 64 + n * 16 + col] = sc[n];
            redi[wave * 64 + n * 16 + col] = cn[n];
        }
    }
    __syncthreads();
    if (wave == 0) {
        const float s = redf[lane] + redf[64 + lane] + redf[128 + lane] + redf[192 + lane];
        const int   c = redi[lane] + redi[64 + lane] + redi[128 + lane] + redi[192 + lane];
        atomicAdd(ws_sums + h * NSTATE + lane, s);
        atomicAdd(ws_cnts + h * NSTATE + lane, c);
        __threadfence();                   // release this block's ws updates
    }
    __syncthreads();

    // last-block-done: the 2048th arrival reduces ws and writes the loss
    if (tid == 0)
        *flag = (atomicAdd(counter, 1) == NBLK - 1) ? 1 : 0;
    __syncthreads();

    if (*flag) {
        __threadfence();                   // acquire: all blocks' ws visible
        float part = 0.0f;
        for (int j = tid; j < NHEAD * NSTATE; j += 256) {
            const float sv = __hip_atomic_load(ws_sums + j, __ATOMIC_RELAXED,
                                               __HIP_MEMORY_SCOPE_AGENT);
            const int   cv = __hip_atomic_load(ws_cnts + j, __ATOMIC_RELAXED,
                                               __HIP_MEMORY_SCOPE_AGENT);
            part += (float)cv * sv;
        }
        #pragma unroll
        for (int d = 1; d <= 32; d <<= 1)
            part += __shfl_xor(part, d);
        if (lane == 0) redl[wave] = part;
        __syncthreads();
        if (tid == 0) {
            const float tot = redl[0] + redl[1] + redl[2] + redl[3];
            const float T = (float)TOKENS;
            out[2 * (size_t)TH] = tot * ((float)NSTATE / (T * T));
        }
    }
}

extern "C" void kernel_launch(void* const* d_in, const int* in_sizes, int n_in,
                              void* d_out, int out_size, void* d_ws, size_t ws_size,
                              hipStream_t stream)
{
    const float* x    = (const float*)d_in[0];
    const float* w    = (const float*)d_in[1];
    const float* bias = (const float*)d_in[2];
    float* out = (float*)d_out;

    float* ws_sums = (float*)d_ws;
    int*   ws_cnts = (int*)((char*)d_ws + 4096);
    int*   counter = (int*)((char*)d_ws + 8192);

    // zero sums+cnts+counter (in-graph: re-zeroed every replay)
    hipMemsetAsync(d_ws, 0, 8192 + sizeof(int), stream);

    router_all<<<dim3(NBLK), dim3(256), 0, stream>>>(x, w, bias, out,
                                                     ws_sums, ws_cnts, counter);
}

// Round 9
// 44.164 us; speedup vs baseline: 2.2775x; 2.2775x over previous
//
#include <hip/hip_runtime.h>

// MultiHeadRouter: B=2, L=4096, H=16, S=64, D=128
// out (float32): [T*H ones][T*H argmax-as-float][1 loss], T = 8192
//
// R9: one-shot wave structure. ALL global traffic via global_load_lds
// (VGPR-free, 16 loads in flight per wave), ONE __syncthreads drain, then a
// pure LDS+MFMA+VALU phase. f16 2-split MFMA chain bit-identical to R4-R8
// (absmax 0). A staged with source-XOR-swizzle (G21) -> conflict-free readback.

#define TOKENS  8192
#define NHEAD   16
#define NSTATE  64
#define DDIM    128
#define TH      (TOKENS * NHEAD)
#define WFRAG_BYTES (1u << 19)   // 512 KB: 16 heads x 32 KB fragment planes

typedef _Float16 half8 __attribute__((ext_vector_type(8)));
typedef float    f32x4 __attribute__((ext_vector_type(4)));

constexpr int TPW   = 16;                    // tokens per wave (one 16x16 m-tile)
constexpr int WAVES = 4;
constexpr int TPB   = TPW * WAVES;           // 64 tokens per block
constexpr int BPH   = TOKENS / TPB;          // 128 blocks per head
constexpr int NBLK  = NHEAD * BPH;           // 2048

#define GLOAD_LDS16(gsrc, ldst)                                           \
    __builtin_amdgcn_global_load_lds(                                     \
        (const __attribute__((address_space(1))) void*)(gsrc),            \
        (__attribute__((address_space(3))) void*)(ldst), 16, 0, 0)

__device__ __forceinline__ unsigned int ordf(float f) {
    unsigned int u = __float_as_uint(f);
    return (u & 0x80000000u) ? ~u : (u | 0x80000000u);   // order-preserving
}

// RNE f32 -> (f16 hi, f16 lo) split of 8 floats (two f32x4)
__device__ __forceinline__ void split8(const f32x4 v0, const f32x4 v1,
                                       half8& hh, half8& ll) {
    #pragma unroll
    for (int j = 0; j < 4; ++j) {
        _Float16 h0 = (_Float16)v0[j];
        hh[j]     = h0;  ll[j]     = (_Float16)(v0[j] - (float)h0);
        _Float16 h1 = (_Float16)v1[j];
        hh[4 + j] = h1;  ll[4 + j] = (_Float16)(v1[j] - (float)h1);
    }
}

// One-shot: w[H,S,D] fp32 -> fragment-ordered f16 hi/lo planes (R7-verified).
// Within head h: fragment (ks*4+n): hi plane at byte (ks*4+n)*2048 + lane*16,
// lo plane at +1024. Lane l holds B(s = n*16 + (l&15), k = ks*32 + (l>>4)*8..+8).
__global__ __launch_bounds__(256)
void prep_w(const float* __restrict__ w, half8* __restrict__ wfrag)
{
    const int t    = blockIdx.x * 256 + threadIdx.x;   // 16384 threads
    const int lane = t & 63;
    const int n    = (t >> 6) & 3;
    const int ks   = (t >> 8) & 3;
    const int h    = t >> 10;
    const int s    = n * 16 + (lane & 15);
    const int k0   = ks * 32 + (lane >> 4) * 8;
    const float* src = w + (size_t)(h * NSTATE + s) * DDIM + k0;
    f32x4 v0 = *reinterpret_cast<const f32x4*>(src);
    f32x4 v1 = *reinterpret_cast<const f32x4*>(src + 4);
    half8 hv, lv;
    split8(v0, v1, hv, lv);
    const size_t hb = (size_t)h * 2048;                // 2048 half8 per head
    const int fb = (ks * 4 + n) * 2;
    wfrag[hb + (size_t)fb * 64 + lane]       = hv;
    wfrag[hb + (size_t)(fb + 1) * 64 + lane] = lv;
}

__global__ __launch_bounds__(256)
void router_mfma(const float* __restrict__ x,      // [T,H,D]
                 const half8* __restrict__ wfrag,  // fragment planes (prep_w)
                 const float* __restrict__ bias,   // [H,S]
                 float* __restrict__ out,
                 float* __restrict__ ws_sums,      // [H,S]
                 int*   __restrict__ ws_cnts)      // [H,S]
{
    // [0,32K): B fragment planes (block-shared). [32K,64K): per-wave A tiles,
    // 16 rows x 512B, source-swizzled (slot ^= tok&7). After MFMA phase the
    // first 2 KB are reused for the block reduction.
    __shared__ __align__(16) unsigned char smem[65536];

    const int blk  = blockIdx.x;
    const int h    = blk >> 7;          // 128 blocks per head
    const int bi   = blk & 127;
    const int tid  = threadIdx.x;
    const int wave = __builtin_amdgcn_readfirstlane(tid >> 6);
    const int lane = tid & 63;
    const int col  = lane & 15;         // A-row (token low bits) == B-state low bits
    const int kg   = lane >> 4;
    const int tokb = bi * TPB + wave * TPW;

    // ---- stage B: 32 KB linear copy of this head's fragment planes ----
    {
        const char* wsrc = (const char*)wfrag + (size_t)h * 32768;
        #pragma unroll
        for (int i = 0; i < 8; ++i) {
            const int off = (wave * 8 + i) * 1024;
            GLOAD_LDS16(wsrc + off + lane * 16, smem + off);
        }
    }

    // ---- stage A: 8 x 1KB (2 token rows each), source-XOR-swizzled ----
    // LDS row r slot s (16B units, 32/row) holds source slot s^(r&7) ->
    // readback at slot (want ^ (r&7)) is 2-way-conflict-free.
    unsigned char* const Aw = smem + 32768 + wave * 8192;
    {
        const size_t srow = (size_t)(NHEAD * DDIM);
        const int tA = lane >> 5;            // 0/1: which of the 2 rows
        const int sA = lane & 31;            // slot within row
        #pragma unroll
        for (int i = 0; i < 8; ++i) {
            const int tok = i * 2 + tA;
            const float* src = x + (size_t)(tokb + tok) * srow + h * DDIM
                             + 4 * (sA ^ (tok & 7));
            GLOAD_LDS16(src, Aw + i * 1024);
        }
    }

    __syncthreads();   // single drain: vmcnt(0) for all 16 staging loads

    f32x4 acc[4];
    #pragma unroll
    for (int n = 0; n < 4; ++n) {
        f32x4 z = {0.f, 0.f, 0.f, 0.f};
        acc[n] = z;
    }

    #pragma unroll
    for (int ks = 0; ks < 4; ++ks) {
        // A fragment for this lane: token row = col, slots ks*8+kg*2 (+1)
        const int s0 = ks * 8 + kg * 2;
        f32x4 a0 = *reinterpret_cast<const f32x4*>(
            Aw + col * 512 + 16 * (s0 ^ (col & 7)));
        f32x4 a1 = *reinterpret_cast<const f32x4*>(
            Aw + col * 512 + 16 * ((s0 + 1) ^ (col & 7)));
        half8 ah, al;
        split8(a0, a1, ah, al);

        #pragma unroll
        for (int n = 0; n < 4; ++n) {
            const int fo = (ks * 4 + n) * 2048 + lane * 16;
            half8 bh = *reinterpret_cast<const half8*>(smem + fo);
            half8 bl = *reinterpret_cast<const half8*>(smem + fo + 1024);
            // same chain order as R4-R8 (bit-identical results)
            acc[n] = __builtin_amdgcn_mfma_f32_16x16x32_f16(ah, bh, acc[n], 0, 0, 0);
            acc[n] = __builtin_amdgcn_mfma_f32_16x16x32_f16(ah, bl, acc[n], 0, 0, 0);
            acc[n] = __builtin_amdgcn_mfma_f32_16x16x32_f16(al, bh, acc[n], 0, 0, 0);
        }
    }

    // ---- epilogue (R4-R8 absmax-0-verified structure) ----
    // C/D layout: col = lane&15 (state low), row = kg*4 + rg -> token tokb+kg*4+rg
    const float b0 = bias[h * NSTATE +  0 + col];
    const float b1 = bias[h * NSTATE + 16 + col];
    const float b2 = bias[h * NSTATE + 32 + col];
    const float b3 = bias[h * NSTATE + 48 + col];

    float sc[4] = {0.f, 0.f, 0.f, 0.f};
    int   cn[4] = {0, 0, 0, 0};

    #pragma unroll
    for (int rg = 0; rg < 4; ++rg) {
        float L0 = acc[0][rg] + b0;
        float L1 = acc[1][rg] + b1;
        float L2 = acc[2][rg] + b2;
        float L3 = acc[3][rg] + b3;

        // exact argmax, lowest-state tie-break: max of (ord(L)<<6 | (63-s))
        unsigned long long k0 = ((unsigned long long)ordf(L0) << 6) | (unsigned)(63 - ( 0 + col));
        unsigned long long k1 = ((unsigned long long)ordf(L1) << 6) | (unsigned)(63 - (16 + col));
        unsigned long long k2 = ((unsigned long long)ordf(L2) << 6) | (unsigned)(63 - (32 + col));
        unsigned long long k3 = ((unsigned long long)ordf(L3) << 6) | (unsigned)(63 - (48 + col));
        unsigned long long ka = k0 > k1 ? k0 : k1;
        unsigned long long kb = k2 > k3 ? k2 : k3;
        unsigned long long kk = ka > kb ? ka : kb;
        #pragma unroll
        for (int d = 1; d <= 8; d <<= 1) {
            unsigned long long o = __shfl_xor(kk, d);
            kk = kk > o ? kk : o;
        }
        const int idx = 63 - (int)(kk & 63ull);

        // softmax scores (no max-subtract: |logit| << 88); feeds loss only
        float e0 = __expf(L0), e1 = __expf(L1), e2 = __expf(L2), e3 = __expf(L3);
        float sm = (e0 + e1) + (e2 + e3);
        #pragma unroll
        for (int d = 1; d <= 8; d <<= 1) sm += __shfl_xor(sm, d);
        const float rinv = __builtin_amdgcn_rcpf(sm);
        sc[0] += e0 * rinv; sc[1] += e1 * rinv;
        sc[2] += e2 * rinv; sc[3] += e3 * rinv;

        cn[0] += (idx ==  0 + col);
        cn[1] += (idx == 16 + col);
        cn[2] += (idx == 32 + col);
        cn[3] += (idx == 48 + col);

        if (col == 0) {
            const int t = tokb + (kg << 2) + rg;
            out[(size_t)t * NHEAD + h] = 1.0f;
            out[(size_t)TH + (size_t)t * NHEAD + h] = (float)idx;
        }
    }

    // wave-level reduction over the 4 kg groups
    #pragma unroll
    for (int n = 0; n < 4; ++n) {
        sc[n] += __shfl_xor(sc[n], 16);
        sc[n] += __shfl_xor(sc[n], 32);
        cn[n] += __shfl_xor(cn[n], 16);
        cn[n] += __shfl_xor(cn[n], 32);
    }

    // block-level reduction (reuse B area; all waves past MFMA at this barrier)
    __syncthreads();
    float* redf = (float*)smem;            // [4][64]
    int*   redi = (int*)(smem + 1024);     // [4][64]
    if (kg == 0) {
        #pragma unroll
        for (int n = 0; n < 4; ++n) {
            redf[wave * 64 + n * 16 + col] = sc[n];
            redi[wave * 64 + n * 16 + col] = cn[n];
        }
    }
    __syncthreads();
    if (wave == 0) {
        const float s = redf[lane] + redf[64 + lane] + redf[128 + lane] + redf[192 + lane];
        const int   c = redi[lane] + redi[64 + lane] + redi[128 + lane] + redi[192 + lane];
        atomicAdd(ws_sums + h * NSTATE + lane, s);
        atomicAdd(ws_cnts + h * NSTATE + lane, c);
    }
}

__global__ void router_loss(const float* __restrict__ ws_sums,
                            const int*   __restrict__ ws_cnts,
                            float* __restrict__ out)
{
    const int tid = threadIdx.x;
    float part = 0.0f;
    for (int j = tid; j < NHEAD * NSTATE; j += 256)
        part += (float)ws_cnts[j] * ws_sums[j];

    #pragma unroll
    for (int k = 32; k >= 1; k >>= 1)
        part += __shfl_xor(part, k);

    __shared__ float red[4];
    const int wv = tid >> 6, lane = tid & 63;
    if (lane == 0) red[wv] = part;
    __syncthreads();
    if (tid == 0) {
        const float tot = red[0] + red[1] + red[2] + red[3];
        const float T = (float)TOKENS;
        out[2 * (size_t)TH] = tot * ((float)NSTATE / (T * T));
    }
}

extern "C" void kernel_launch(void* const* d_in, const int* in_sizes, int n_in,
                              void* d_out, int out_size, void* d_ws, size_t ws_size,
                              hipStream_t stream)
{
    const float* x    = (const float*)d_in[0];
    const float* w    = (const float*)d_in[1];
    const float* bias = (const float*)d_in[2];
    float* out = (float*)d_out;

    half8* wfrag   = (half8*)d_ws;
    float* ws_sums = (float*)((char*)d_ws + WFRAG_BYTES);
    int*   ws_cnts = (int*)((char*)d_ws + WFRAG_BYTES + 4096);

    hipMemsetAsync((char*)d_ws + WFRAG_BYTES, 0, 8192, stream);

    prep_w<<<dim3(64), dim3(256), 0, stream>>>(w, wfrag);
    router_mfma<<<dim3(NBLK), dim3(256), 0, stream>>>(x, wfrag, bias, out,
                                                      ws_sums, ws_cnts);
    router_loss<<<dim3(1), dim3(256), 0, stream>>>(ws_sums, ws_cnts, out);
}

// Round 10
// 34.935 us; speedup vs baseline: 2.8791x; 1.2642x over previous
//
#include <hip/hip_runtime.h>

// MultiHeadRouter: B=2, L=4096, H=16, S=64, D=128
// out (float32): [T*H ones][T*H argmax-as-float][1 loss], T = 8192
//
// R10 = R7 structure + BI-MAJOR grid order.
// Grid order is the change under test: blk = bi*16 + h (was h-major). The
// ~1300 concurrently-resident blocks now read a contiguous sliding window of
// x (all 16 heads of the same token range) instead of sparsely touching the
// whole 64 MB footprint at 1/16 density -> DRAM row locality + L3 window.
// f16 2-split MFMA chain + epilogue bit-identical to R4-R9 (absmax 0 x6).

#define TOKENS  8192
#define NHEAD   16
#define NSTATE  64
#define DDIM    128
#define TH      (TOKENS * NHEAD)
#define WFRAG_BYTES (1u << 19)   // 512 KB: 16 heads x 32 KB fragment planes

typedef _Float16 half8 __attribute__((ext_vector_type(8)));
typedef float    f32x4 __attribute__((ext_vector_type(4)));

constexpr int TPW   = 16;                    // tokens per wave (one 16x16 m-tile)
constexpr int WAVES = 4;
constexpr int TPB   = TPW * WAVES;           // 64 tokens per block
constexpr int BPH   = TOKENS / TPB;          // 128 blocks per head
constexpr int NBLK  = NHEAD * BPH;           // 2048

#define GLOAD_LDS16(gsrc, ldst)                                           \
    __builtin_amdgcn_global_load_lds(                                     \
        (const __attribute__((address_space(1))) void*)(gsrc),            \
        (__attribute__((address_space(3))) void*)(ldst), 16, 0, 0)

__device__ __forceinline__ unsigned int ordf(float f) {
    unsigned int u = __float_as_uint(f);
    return (u & 0x80000000u) ? ~u : (u | 0x80000000u);   // order-preserving
}

// RNE f32 -> (f16 hi, f16 lo) split of 8 floats (two f32x4)
__device__ __forceinline__ void split8(const f32x4 v0, const f32x4 v1,
                                       half8& hh, half8& ll) {
    #pragma unroll
    for (int j = 0; j < 4; ++j) {
        _Float16 h0 = (_Float16)v0[j];
        hh[j]     = h0;  ll[j]     = (_Float16)(v0[j] - (float)h0);
        _Float16 h1 = (_Float16)v1[j];
        hh[4 + j] = h1;  ll[4 + j] = (_Float16)(v1[j] - (float)h1);
    }
}

// One-shot: w[H,S,D] fp32 -> fragment-ordered f16 hi/lo planes (R7-verified).
// Within head h: fragment (ks*4+n): hi plane at byte (ks*4+n)*2048 + lane*16,
// lo plane at +1024. Lane l holds B(s = n*16 + (l&15), k = ks*32 + (l>>4)*8..+8).
__global__ __launch_bounds__(256)
void prep_w(const float* __restrict__ w, half8* __restrict__ wfrag)
{
    const int t    = blockIdx.x * 256 + threadIdx.x;   // 16384 threads
    const int lane = t & 63;
    const int n    = (t >> 6) & 3;
    const int ks   = (t >> 8) & 3;
    const int h    = t >> 10;
    const int s    = n * 16 + (lane & 15);
    const int k0   = ks * 32 + (lane >> 4) * 8;
    const float* src = w + (size_t)(h * NSTATE + s) * DDIM + k0;
    f32x4 v0 = *reinterpret_cast<const f32x4*>(src);
    f32x4 v1 = *reinterpret_cast<const f32x4*>(src + 4);
    half8 hv, lv;
    split8(v0, v1, hv, lv);
    const size_t hb = (size_t)h * 2048;                // 2048 half8 per head
    const int fb = (ks * 4 + n) * 2;
    wfrag[hb + (size_t)fb * 64 + lane]       = hv;
    wfrag[hb + (size_t)(fb + 1) * 64 + lane] = lv;
}

__global__ __launch_bounds__(256)
void router_mfma(const float* __restrict__ x,      // [T,H,D]
                 const half8* __restrict__ wfrag,  // fragment planes (prep_w)
                 const float* __restrict__ bias,   // [H,S]
                 float* __restrict__ out,
                 float* __restrict__ ws_sums,      // [H,S]
                 int*   __restrict__ ws_cnts)      // [H,S]
{
    // 32 KB: B fragment planes only -> 5 blocks/CU by LDS.
    // First 2 KB reused for the block reduction after the MFMA phase.
    __shared__ __align__(16) unsigned char smem[32768];

    const int blk  = blockIdx.x;
    const int h    = blk & 15;          // BI-MAJOR: concurrent blocks = all heads
    const int bi   = blk >> 4;          //           of the same token window
    const int tid  = threadIdx.x;
    const int wave = __builtin_amdgcn_readfirstlane(tid >> 6);
    const int lane = tid & 63;
    const int col  = lane & 15;         // A-row (token low bits) == B-state low bits
    const int kg   = lane >> 4;
    const int tokb = bi * TPB + wave * TPW;

    // ---- A first: 8 x dwordx4 global->VGPR (HBM, longest latency) ----
    const size_t srow = (size_t)(NHEAD * DDIM);
    const float* arow = x + (size_t)(tokb + col) * srow + h * DDIM + kg * 8;

    f32x4 g[4][2];
    #pragma unroll
    for (int ks = 0; ks < 4; ++ks) {
        g[ks][0] = *reinterpret_cast<const f32x4*>(arow + ks * 32);
        g[ks][1] = *reinterpret_cast<const f32x4*>(arow + ks * 32 + 4);
    }

    // ---- B: 32 KB linear copy of this head's fragment planes (L2-hot) ----
    {
        const char* wsrc = (const char*)wfrag + (size_t)h * 32768;
        #pragma unroll
        for (int i = 0; i < 8; ++i) {
            const int off = (wave * 8 + i) * 1024;
            GLOAD_LDS16(wsrc + off + lane * 16, smem + off);
        }
    }

    __syncthreads();   // drains A+B; only barrier before the reduction

    f32x4 acc[4];
    #pragma unroll
    for (int n = 0; n < 4; ++n) {
        f32x4 z = {0.f, 0.f, 0.f, 0.f};
        acc[n] = z;
    }

    #pragma unroll
    for (int ks = 0; ks < 4; ++ks) {
        // split inside the loop: g[ks] dies progressively, lower reg peak
        half8 ah, al;
        split8(g[ks][0], g[ks][1], ah, al);
        #pragma unroll
        for (int n = 0; n < 4; ++n) {
            const int fo = (ks * 4 + n) * 2048 + lane * 16;
            half8 bh = *reinterpret_cast<const half8*>(smem + fo);
            half8 bl = *reinterpret_cast<const half8*>(smem + fo + 1024);
            // same chain order as R4-R9 (bit-identical results)
            acc[n] = __builtin_amdgcn_mfma_f32_16x16x32_f16(ah, bh, acc[n], 0, 0, 0);
            acc[n] = __builtin_amdgcn_mfma_f32_16x16x32_f16(ah, bl, acc[n], 0, 0, 0);
            acc[n] = __builtin_amdgcn_mfma_f32_16x16x32_f16(al, bh, acc[n], 0, 0, 0);
        }
    }

    // ---- epilogue (R4-R9 absmax-0-verified structure) ----
    // C/D layout: col = lane&15 (state low), row = kg*4 + rg -> token tokb+kg*4+rg
    const float b0 = bias[h * NSTATE +  0 + col];
    const float b1 = bias[h * NSTATE + 16 + col];
    const float b2 = bias[h * NSTATE + 32 + col];
    const float b3 = bias[h * NSTATE + 48 + col];

    float sc[4] = {0.f, 0.f, 0.f, 0.f};
    int   cn[4] = {0, 0, 0, 0};

    #pragma unroll
    for (int rg = 0; rg < 4; ++rg) {
        float L0 = acc[0][rg] + b0;
        float L1 = acc[1][rg] + b1;
        float L2 = acc[2][rg] + b2;
        float L3 = acc[3][rg] + b3;

        // exact argmax, lowest-state tie-break: max of (ord(L)<<6 | (63-s))
        unsigned long long k0 = ((unsigned long long)ordf(L0) << 6) | (unsigned)(63 - ( 0 + col));
        unsigned long long k1 = ((unsigned long long)ordf(L1) << 6) | (unsigned)(63 - (16 + col));
        unsigned long long k2 = ((unsigned long long)ordf(L2) << 6) | (unsigned)(63 - (32 + col));
        unsigned long long k3 = ((unsigned long long)ordf(L3) << 6) | (unsigned)(63 - (48 + col));
        unsigned long long ka = k0 > k1 ? k0 : k1;
        unsigned long long kb = k2 > k3 ? k2 : k3;
        unsigned long long kk = ka > kb ? ka : kb;
        #pragma unroll
        for (int d = 1; d <= 8; d <<= 1) {
            unsigned long long o = __shfl_xor(kk, d);
            kk = kk > o ? kk : o;
        }
        const int idx = 63 - (int)(kk & 63ull);

        // softmax scores (no max-subtract: |logit| << 88); feeds loss only
        float e0 = __expf(L0), e1 = __expf(L1), e2 = __expf(L2), e3 = __expf(L3);
        float sm = (e0 + e1) + (e2 + e3);
        #pragma unroll
        for (int d = 1; d <= 8; d <<= 1) sm += __shfl_xor(sm, d);
        const float rinv = __builtin_amdgcn_rcpf(sm);
        sc[0] += e0 * rinv; sc[1] += e1 * rinv;
        sc[2] += e2 * rinv; sc[3] += e3 * rinv;

        cn[0] += (idx ==  0 + col);
        cn[1] += (idx == 16 + col);
        cn[2] += (idx == 32 + col);
        cn[3] += (idx == 48 + col);

        if (col == 0) {
            const int t = tokb + (kg << 2) + rg;
            out[(size_t)t * NHEAD + h] = 1.0f;
            out[(size_t)TH + (size_t)t * NHEAD + h] = (float)idx;
        }
    }

    // wave-level reduction over the 4 kg groups
    #pragma unroll
    for (int n = 0; n < 4; ++n) {
        sc[n] += __shfl_xor(sc[n], 16);
        sc[n] += __shfl_xor(sc[n], 32);
        cn[n] += __shfl_xor(cn[n], 16);
        cn[n] += __shfl_xor(cn[n], 32);
    }

    // block-level reduction (reuse B area; all waves past MFMA at this barrier)
    __syncthreads();
    float* redf = (float*)smem;            // [4][64]
    int*   redi = (int*)(smem + 1024);     // [4][64]
    if (kg == 0) {
        #pragma unroll
        for (int n = 0; n < 4; ++n) {
            redf[wave * 64 + n * 16 + col] = sc[n];
            redi[wave * 64 + n * 16 + col] = cn[n];
        }
    }
    __syncthreads();
    if (wave == 0) {
        const float s = redf[lane] + redf[64 + lane] + redf[128 + lane] + redf[192 + lane];
        const int   c = redi[lane] + redi[64 + lane] + redi[128 + lane] + redi[192 + lane];
        atomicAdd(ws_sums + h * NSTATE + lane, s);
        atomicAdd(ws_cnts + h * NSTATE + lane, c);
    }
}

__global__ void router_loss(const float* __restrict__ ws_sums,
                            const int*   __restrict__ ws_cnts,
                            float* __restrict__ out)
{
    const int tid = threadIdx.x;
    float part = 0.0f;
    for (int j = tid; j < NHEAD * NSTATE; j += 256)
        part += (float)ws_cnts[j] * ws_sums[j];

    #pragma unroll
    for (int k = 32; k >= 1; k >>= 1)
        part += __shfl_xor(part, k);

    __shared__ float red[4];
    const int wv = tid >> 6, lane = tid & 63;
    if (lane == 0) red[wv] = part;
    __syncthreads();
    if (tid == 0) {
        const float tot = red[0] + red[1] + red[2] + red[3];
        const float T = (float)TOKENS;
        out[2 * (size_t)TH] = tot * ((float)NSTATE / (T * T));
    }
}

extern "C" void kernel_launch(void* const* d_in, const int* in_sizes, int n_in,
                              void* d_out, int out_size, void* d_ws, size_t ws_size,
                              hipStream_t stream)
{
    const float* x    = (const float*)d_in[0];
    const float* w    = (const float*)d_in[1];
    const float* bias = (const float*)d_in[2];
    float* out = (float*)d_out;

    half8* wfrag   = (half8*)d_ws;
    float* ws_sums = (float*)((char*)d_ws + WFRAG_BYTES);
    int*   ws_cnts = (int*)((char*)d_ws + WFRAG_BYTES + 4096);

    hipMemsetAsync((char*)d_ws + WFRAG_BYTES, 0, 8192, stream);

    prep_w<<<dim3(64), dim3(256), 0, stream>>>(w, wfrag);
    router_mfma<<<dim3(NBLK), dim3(256), 0, stream>>>(x, wfrag, bias, out,
                                                      ws_sums, ws_cnts);
    router_loss<<<dim3(1), dim3(256), 0, stream>>>(ws_sums, ws_cnts, out);
}